// Round 11
// baseline (337.772 us; speedup 1.0000x reference)
//
#include <hip/hip_runtime.h>
#include <stdint.h>

// Koopman autoencoder — round 11 (MI355X / gfx950).
// R10 structure with k_pred grid bug fixed (rtile range [0,32): 2048 samples).
// Fused enc+dec kernel: weights streamed from L2 via 2-deep register rotation
// (loadW next -> mm cur -> PIN -> barrier), 3 blocks/CU, pe in LDS, pd in regs.

typedef _Float16 h8 __attribute__((ext_vector_type(8)));
typedef _Float16 h4 __attribute__((ext_vector_type(4)));
typedef float    f4 __attribute__((ext_vector_type(4)));

#define ROWS_AUTO 104448
#define NT64      1632           // 64-row tiles

// half-element offsets inside wt (all mats stored as W^T [n][k])
#define WT_ENCW      0
#define WT_ENCWOUT   (4*16384)
#define WT_DECW      (5*16384)
#define WT_DECWOUT   (9*16384)
#define WT_COMB      (10*16384)  // (WencI@WdecI)^T [128][128]

// ws byte offsets
#define MFULL_OFF_B 0x60000      // f16 [50][128][128] (WencI@L^{s+1}@WdecI)^T
#define ACH_OFF_B   0x200000     // f32 [50][441]
#define PET0_OFF_B  0x220000     // f16 [2048][128] compact pe at t=0 (chunk-linear)

// LDS buffers (byte offsets): LA/LB/LC 16KB each; trbuf spans LB+LC (32KB)
#define LA 0
#define LB 16384
#define LC 32768
#define LDSM (49152 + 2560)      // main: + 1280 f16 biases
#define LDSP (49152 + 1280)      // pred: + 640 f16 biases

// main bias half-offsets
#define ENC_B  0
#define ENC_BO 512
#define DEC_B  640
#define DEC_BO 1152

#define hsw(rl, c) ((rl)*256 + ((((c)) ^ ((rl) & 7)) << 4))

// opaque use: forces loads materialized (no sinking/remat into the loop)
#define PIN(B) asm volatile("" : "+v"(B[0]), "+v"(B[1]), "+v"(B[2]), "+v"(B[3]), \
                                 "+v"(B[4]), "+v"(B[5]), "+v"(B[6]), "+v"(B[7]))

__device__ __forceinline__ f4 mfma16(h8 a, h8 b, f4 c) {
  return __builtin_amdgcn_mfma_f32_16x16x32_f16(a, b, c, 0, 0, 0);
}
__device__ __forceinline__ h8 cvt8(f4 a, f4 b) {
  h8 r;
  r[0]=(_Float16)a[0]; r[1]=(_Float16)a[1]; r[2]=(_Float16)a[2]; r[3]=(_Float16)a[3];
  r[4]=(_Float16)b[0]; r[5]=(_Float16)b[1]; r[6]=(_Float16)b[2]; r[7]=(_Float16)b[3];
  return r;
}
// wave's 32-col slice of a 128x128 W^T
__device__ __forceinline__ void loadW(h8 B[8], const _Float16* gW, int nbase, int r15, int hi) {
#pragma unroll
  for (int nt = 0; nt < 2; ++nt)
#pragma unroll
    for (int ks = 0; ks < 4; ++ks)
      B[nt*4+ks] = *(const h8*)(gW + (size_t)(nbase + nt*16 + r15)*128 + ks*32 + hi*8);
}

// SWAPPED operands: lane holds out[row=rt*16+r15][n=wbase+nt*16+hi*4+d]
__device__ __forceinline__ void mmF4s(const char* sm, int hb, const h8 B[8],
                                      f4 acc[4][2], int r15, int hi) {
#pragma unroll
  for (int rt = 0; rt < 4; ++rt) { acc[rt][0] = (f4){0,0,0,0}; acc[rt][1] = (f4){0,0,0,0}; }
#pragma unroll
  for (int ks = 0; ks < 4; ++ks) {
    int c = ks*4 + hi;
    h8 a[4];
#pragma unroll
    for (int rt = 0; rt < 4; ++rt) a[rt] = *(const h8*)(sm + hb + hsw(rt*16 + r15, c));
#pragma unroll
    for (int rt = 0; rt < 4; ++rt) {
      acc[rt][0] = mfma16(B[ks],   a[rt], acc[rt][0]);
      acc[rt][1] = mfma16(B[4+ks], a[rt], acc[rt][1]);
    }
  }
}

// ReLU(acc + f16 bias) -> h[hb] via b64 writes
__device__ __forceinline__ void hw4s(char* sm, int hb, int wbase, const f4 acc[4][2],
                                     const _Float16* blh, int bo, int r15, int hi) {
  h4 b0 = *(const h4*)(blh + bo + wbase + hi*4);
  h4 b1 = *(const h4*)(blh + bo + wbase + 16 + hi*4);
  int bo2 = (hi & 1) * 8;
#pragma unroll
  for (int nt = 0; nt < 2; ++nt) {
    int c = ((wbase + nt*16) >> 3) + (hi >> 1);
    h4 bb = nt ? b1 : b0;
#pragma unroll
    for (int rt = 0; rt < 4; ++rt) {
      int row = rt*16 + r15;
      h4 p;
#pragma unroll
      for (int d = 0; d < 4; ++d) p[d] = (_Float16)fmaxf(acc[rt][nt][d] + (float)bb[d], 0.f);
      *(h4*)(sm + hb + row*256 + ((c ^ (row & 7)) << 4) + bo2) = p;
    }
  }
}
// raw regs -> h[hb]
__device__ __forceinline__ void hw4r(char* sm, int hb, int wbase, const h4 pr[4][2],
                                     int r15, int hi) {
  int bo2 = (hi & 1) * 8;
#pragma unroll
  for (int nt = 0; nt < 2; ++nt) {
    int c = ((wbase + nt*16) >> 3) + (hi >> 1);
#pragma unroll
    for (int rt = 0; rt < 4; ++rt) {
      int row = rt*16 + r15;
      *(h4*)(sm + hb + row*256 + ((c ^ (row & 7)) << 4) + bo2) = pr[rt][nt];
    }
  }
}

// out = acc + bout + skip -> trbuf f32 (LB..LC span) -> global full lines.
// SKIP==0: skip from LDS buf hskip; SKIP==1: skip from regs pr.
template<int SKIP>
__device__ __forceinline__ void epi_store(char* sm, int hskip, const h4 pr[4][2], int wbase,
                                          const f4 acc[4][2], const _Float16* blh, int bout,
                                          float* dst, int rstride, int tid, int r15, int hi) {
  h4 b0 = *(const h4*)(blh + bout + wbase + hi*4);
  h4 b1 = *(const h4*)(blh + bout + wbase + 16 + hi*4);
  int bo2 = (hi & 1) * 8;
#pragma unroll
  for (int nt = 0; nt < 2; ++nt) {
    int c = ((wbase + nt*16) >> 3) + (hi >> 1);
    int q = (wbase >> 2) + nt*4 + hi;
    h4 bb = nt ? b1 : b0;
#pragma unroll
    for (int rt = 0; rt < 4; ++rt) {
      int row = rt*16 + r15;
      h4 sk = SKIP ? pr[rt][nt]
                   : *(const h4*)(sm + hskip + row*256 + ((c ^ (row & 7)) << 4) + bo2);
      f4 v;
#pragma unroll
      for (int d = 0; d < 4; ++d) v[d] = acc[rt][nt][d] + (float)bb[d] + (float)sk[d];
      *(f4*)(sm + LB + row*512 + ((q ^ ((row & 7) << 2)) << 4)) = v;
    }
  }
  __syncthreads();
#pragma unroll
  for (int i = 0; i < 8; ++i) {
    int idx = i*256 + tid, row = idx >> 5, q = idx & 31;
    f4 v = *(const f4*)(sm + LB + row*512 + ((q ^ ((row & 7) << 2)) << 4));
    *(f4*)(dst + (size_t)row*rstride + q*4) = v;
  }
}

// one hidden layer phase with next-weight stream
#define PHASE(LIN, LOUT, BC, BN, NXT, BO) do {            \
    loadW(BN, NXT, wbase, r15, hi);                        \
    mmF4s(sm, LIN, BC, acc, r15, hi);                      \
    hw4s(sm, LOUT, wbase, acc, blh, BO, r15, hi);          \
    PIN(BN);                                               \
    __syncthreads();                                       \
  } while (0)

// ---------------- prep kernels ----------------

__global__ __launch_bounds__(512) void k_prep(
    const float* __restrict__ encW, const float* __restrict__ encWout,
    const float* __restrict__ decW, const float* __restrict__ decWout,
    const float* __restrict__ L,
    _Float16* __restrict__ wt, float* __restrict__ ach) {
  __shared__ float chA[441], chB[441];
  int m = blockIdx.y, tid = threadIdx.x;
  if (m == 10) {
    if (blockIdx.x != 0) return;
    if (tid < 441) chA[tid] = L[tid];
    __syncthreads();
    for (int s = 0; s < 50; ++s) {
      if (tid < 441) ach[s*441 + tid] = chA[tid];
      if (s == 49) break;
      if (tid < 441) {
        int i = tid / 21, j = tid % 21; float a = 0.f;
        for (int k = 0; k < 21; ++k) a += chA[i*21 + k] * L[k*21 + j];
        chB[tid] = a;
      }
      __syncthreads();
      if (tid < 441) chA[tid] = chB[tid];
      __syncthreads();
    }
    return;
  }
  int idx = blockIdx.x*512 + tid;
  if (idx >= 16384) return;
  const float* src; _Float16* dst;
  if (m < 4)       { src = encW + m*16384;     dst = wt + WT_ENCW + m*16384; }
  else if (m == 4) { src = encWout;            dst = wt + WT_ENCWOUT; }
  else if (m < 9)  { src = decW + (m-5)*16384; dst = wt + WT_DECW + (m-5)*16384; }
  else             { src = decWout;            dst = wt + WT_DECWOUT; }
  int n = idx >> 7, k = idx & 127;
  dst[idx] = (_Float16)src[k*128 + n];            // W^T[n][k]
}

__global__ __launch_bounds__(512) void k_aux(
    const float* __restrict__ ach, const float* __restrict__ wencI,
    const float* __restrict__ wdecI,
    _Float16* __restrict__ mfull, _Float16* __restrict__ wt) {
  __shared__ float T1[2688];
  __shared__ float sa[441];
  int s = blockIdx.x, t = threadIdx.x;
  if (s < 50) {
    if (t < 441) sa[t] = ach[s*441 + t];
    __syncthreads();
    for (int idx = t; idx < 2688; idx += 512) {
      int k = idx / 21, j = idx % 21;
      float a = 0.f;
      for (int u = 0; u < 21; ++u) a += wencI[k*21 + u] * sa[u*21 + j];
      T1[idx] = a;
    }
  } else {
    for (int idx = t; idx < 2688; idx += 512) T1[idx] = wencI[idx];
  }
  __syncthreads();
  _Float16* dst = (s < 50) ? (mfull + (size_t)s*16384) : (wt + WT_COMB);
  for (int idx = t; idx < 16384; idx += 512) {    // M^T[n][k]
    int n = idx >> 7, k = idx & 127;
    float a = 0.f;
    for (int j = 0; j < 21; ++j) a += T1[k*21 + j] * wdecI[j*128 + n];
    dst[idx] = (_Float16)a;
  }
}

// ---------------- fused main: x -> out1, out2, pet0 ----------------

__global__ __launch_bounds__(256, 3) void k_main(
    const float* __restrict__ x, const _Float16* __restrict__ wt,
    const float* __restrict__ enc_b, const float* __restrict__ enc_bout,
    const float* __restrict__ dec_b, const float* __restrict__ dec_bout,
    float* __restrict__ out1, float* __restrict__ out2, _Float16* __restrict__ pet0) {
  __shared__ char sm[LDSM];
  _Float16* blh = (_Float16*)(sm + 49152);
  int tid = threadIdx.x, lane = tid & 63;
  int r15 = lane & 15, hi = lane >> 4;
  int wbase = (tid >> 6) * 32;
  h8 Ba[8], Bb[8];
  f4 acc[4][2];
  h4 pd[4][2];

  for (int i = tid; i < 1280; i += 256) {          // f16 biases
    float v;
    if (i < 512) v = enc_b[i];
    else if (i < 640) v = enc_bout[i - 512];
    else if (i < 1152) v = dec_b[i - 640];
    else v = dec_bout[i - 1152];
    blh[i] = (_Float16)v;
  }
  loadW(Ba, wt + WT_ENCW, wbase, r15, hi);         // prologue: enc L0

  for (int t = blockIdx.x; t < NT64; t += gridDim.x) {
    size_t rb = (size_t)t * 64;
#pragma unroll
    for (int i = 0; i < 4; ++i) {                  // stage x -> LA (enc skip)
      int idx = i*256 + tid, rl = idx >> 4, c = idx & 15;
      const float* s = x + (rb + rl)*128 + c*8;
      f4 v0 = *(const f4*)s, v1 = *(const f4*)(s + 4);
      *(h8*)(sm + LA + hsw(rl, c)) = cvt8(v0, v1);
    }
    PIN(Ba);
    __syncthreads();
    // encoder
    PHASE(LA, LB, Ba, Bb, wt + WT_ENCW + 16384,   ENC_B + 0);
    PHASE(LB, LC, Bb, Ba, wt + WT_ENCW + 2*16384, ENC_B + 128);
    PHASE(LC, LB, Ba, Bb, wt + WT_ENCW + 3*16384, ENC_B + 256);
    PHASE(LB, LC, Bb, Ba, wt + WT_ENCWOUT,        ENC_B + 384);
    loadW(Bb, wt + WT_COMB, wbase, r15, hi);
    mmF4s(sm, LC, Ba, acc, r15, hi);               // encWout
    {                                              // pe = acc + bout + x, in-place LA
      h4 b0 = *(const h4*)(blh + ENC_BO + wbase + hi*4);
      h4 b1 = *(const h4*)(blh + ENC_BO + wbase + 16 + hi*4);
      int bo2 = (hi & 1) * 8;
#pragma unroll
      for (int nt = 0; nt < 2; ++nt) {
        int c = ((wbase + nt*16) >> 3) + (hi >> 1);
        h4 bb = nt ? b1 : b0;
#pragma unroll
        for (int rt = 0; rt < 4; ++rt) {
          int row = rt*16 + r15;
          int soff = LA + row*256 + ((c ^ (row & 7)) << 4) + bo2;
          h4 sk = *(const h4*)(sm + soff);
          h4 p;
#pragma unroll
          for (int d = 0; d < 4; ++d) p[d] = (_Float16)(acc[rt][nt][d] + (float)bb[d] + (float)sk[d]);
          *(h4*)(sm + soff) = p;                   // thread-private slot: no race
        }
      }
    }
    PIN(Bb);
    __syncthreads();
    {                                              // pet0 extraction (reads LA)
#pragma unroll
      for (int i = 0; i < 4; ++i) {
        int idx = i*256 + tid, rl = idx >> 4, slot = idx & 15;
        size_t rg = rb + (size_t)rl;
        if (rg % 51u == 0u) {
          int c = slot ^ (rl & 7);                 // unswizzle -> chunk-linear
          *(f4*)((char*)pet0 + (rg/51u)*256 + c*16) = *(const f4*)(sm + LA + idx*16);
        }
      }
    }
    loadW(Ba, wt + WT_DECW, wbase, r15, hi);       // dec L0
    mmF4s(sm, LA, Bb, acc, r15, hi);               // pd = pe @ comb -> regs
#pragma unroll
    for (int rt = 0; rt < 4; ++rt)
#pragma unroll
      for (int nt = 0; nt < 2; ++nt)
#pragma unroll
        for (int d = 0; d < 4; ++d) pd[rt][nt][d] = (_Float16)acc[rt][nt][d];
    // dec stream B (input+skip pe=LA; LB free since enc L3 barrier)
    PHASE(LA, LB, Ba, Bb, wt + WT_DECW + 16384,   DEC_B + 0);
    PHASE(LB, LC, Bb, Ba, wt + WT_DECW + 2*16384, DEC_B + 128);
    PHASE(LC, LB, Ba, Bb, wt + WT_DECW + 3*16384, DEC_B + 256);
    PHASE(LB, LC, Bb, Ba, wt + WT_DECWOUT,        DEC_B + 384);
    loadW(Bb, wt + WT_DECW, wbase, r15, hi);       // dec L0 again (stream A)
    mmF4s(sm, LC, Ba, acc, r15, hi);               // decWout
    PIN(Bb);
    __syncthreads();                               // LB/LC reads done -> trbuf safe
    epi_store<0>(sm, LA, pd, wbase, acc, blh, DEC_BO,
                 out2 + rb*128, 128, tid, r15, hi);
    hw4r(sm, LA, wbase, pd, r15, hi);              // pd -> LA (LA skip reads done)
    __syncthreads();
    // dec stream A (input LA=pd, skip pd regs)
    PHASE(LA, LB, Bb, Ba, wt + WT_DECW + 16384,   DEC_B + 0);
    PHASE(LB, LC, Ba, Bb, wt + WT_DECW + 2*16384, DEC_B + 128);
    PHASE(LC, LB, Bb, Ba, wt + WT_DECW + 3*16384, DEC_B + 256);
    PHASE(LB, LC, Ba, Bb, wt + WT_DECWOUT,        DEC_B + 384);
    loadW(Ba, wt + WT_ENCW, wbase, r15, hi);       // next tile enc L0
    mmF4s(sm, LC, Bb, acc, r15, hi);               // decWout
    PIN(Ba);
    __syncthreads();
    epi_store<1>(sm, 0, pd, wbase, acc, blh, DEC_BO,
                 out1 + rb*128, 128, tid, r15, hi);
    __syncthreads();                               // trbuf reads done before next tile
  }
}

// ---------------- prediction: pet0 @ Mfull_s -> dec -> out3 ----------------
// grid 800 = 32 rtiles (64 rows each -> 2048 samples) x 25 chunks x 2 steps

__global__ __launch_bounds__(256, 3) void k_pred(
    const _Float16* __restrict__ pet0, const _Float16* __restrict__ wt,
    const _Float16* __restrict__ mfull,
    const float* __restrict__ dec_b, const float* __restrict__ dec_bout,
    float* __restrict__ out3) {
  __shared__ char sm[LDSP];
  _Float16* blh = (_Float16*)(sm + 49152);
  int tid = threadIdx.x, lane = tid & 63;
  int r15 = lane & 15, hi = lane >> 4;
  int wbase = (tid >> 6) * 32;
  h8 Ba[8], Bb[8];
  f4 acc[4][2];
  h4 di[4][2];

  for (int i = tid; i < 640; i += 256)
    blh[i] = (_Float16)(i < 512 ? dec_b[i] : dec_bout[i - 512]);

  int rtile = blockIdx.x / 25;                     // [0,32)
  int chunk = blockIdx.x % 25;                     // [0,25)
  int s0 = chunk * 2;
  loadW(Ba, mfull + (size_t)s0*16384, wbase, r15, hi);
#pragma unroll
  for (int i = 0; i < 4; ++i) {                    // stage pet0 -> LA (persistent)
    int idx = i*256 + tid, rl = idx >> 4, c = idx & 15;
    f4 v = *(const f4*)((const char*)pet0 + (size_t)(rtile*64 + rl)*256 + c*16);
    *(f4*)(sm + LA + hsw(rl, c)) = v;
  }
  PIN(Ba);
  __syncthreads();

  for (int s = s0; s < s0 + 2; ++s) {
    loadW(Bb, wt + WT_DECW, wbase, r15, hi);
    mmF4s(sm, LA, Ba, acc, r15, hi);               // di = pet0 @ Mfull_s
#pragma unroll
    for (int rt = 0; rt < 4; ++rt)
#pragma unroll
      for (int nt = 0; nt < 2; ++nt)
#pragma unroll
        for (int d = 0; d < 4; ++d) di[rt][nt][d] = (_Float16)acc[rt][nt][d];
    hw4r(sm, LB, wbase, di, r15, hi);              // di -> LB (input)
    PIN(Bb);
    __syncthreads();
    PHASE(LB, LC, Bb, Ba, wt + WT_DECW + 16384,   0);
    PHASE(LC, LB, Ba, Bb, wt + WT_DECW + 2*16384, 128);
    PHASE(LB, LC, Bb, Ba, wt + WT_DECW + 3*16384, 256);
    PHASE(LC, LB, Ba, Bb, wt + WT_DECWOUT,        384);
    {
      int sn = (s + 1 < 50) ? s + 1 : 49;
      loadW(Ba, mfull + (size_t)sn*16384, wbase, r15, hi);
    }
    mmF4s(sm, LB, Bb, acc, r15, hi);               // decWout
    PIN(Ba);
    __syncthreads();                               // LB/LC reads done -> trbuf safe
    epi_store<1>(sm, 0, di, wbase, acc, blh, 512,
                 out3 + ((size_t)rtile*64*50 + s)*128, 50*128, tid, r15, hi);
    __syncthreads();                               // trbuf reads done before next s
  }
}

// ---------------- launch ----------------

extern "C" void kernel_launch(void* const* d_in, const int* in_sizes, int n_in,
                              void* d_out, int out_size, void* d_ws, size_t ws_size,
                              hipStream_t stream) {
  const float* x        = (const float*)d_in[0];
  const float* encW     = (const float*)d_in[1];
  const float* enc_b    = (const float*)d_in[2];
  const float* encWout  = (const float*)d_in[3];
  const float* enc_bout = (const float*)d_in[4];
  const float* decW     = (const float*)d_in[5];
  const float* dec_b    = (const float*)d_in[6];
  const float* decWout  = (const float*)d_in[7];
  const float* dec_bout = (const float*)d_in[8];
  const float* wencI    = (const float*)d_in[9];
  const float* L        = (const float*)d_in[10];
  const float* wdecI    = (const float*)d_in[11];

  char* ws = (char*)d_ws;
  _Float16* wt    = (_Float16*)ws;
  _Float16* mfull = (_Float16*)(ws + MFULL_OFF_B);
  float*    ach   = (float*)(ws + ACH_OFF_B);
  _Float16* pet0  = (_Float16*)(ws + PET0_OFF_B);

  float* out1 = (float*)d_out;                       // autoencoder_output
  float* out2 = out1 + (size_t)ROWS_AUTO*128;        // outer_auto_output
  float* out3 = out2 + (size_t)ROWS_AUTO*128;        // predictions [2048][50][128]

  hipLaunchKernelGGL(k_prep, dim3(32, 11), dim3(512), 0, stream,
                     encW, encWout, decW, decWout, L, wt, ach);
  hipLaunchKernelGGL(k_aux, dim3(51), dim3(512), 0, stream,
                     ach, wencI, wdecI, mfull, wt);
  hipLaunchKernelGGL(k_main, dim3(768), dim3(256), 0, stream,
                     x, wt, enc_b, enc_bout, dec_b, dec_bout, out1, out2, pet0);
  hipLaunchKernelGGL(k_pred, dim3(800), dim3(256), 0, stream,
                     pet0, wt, mfull, dec_b, dec_bout, out3);
}

// Round 12
// 225.534 us; speedup vs baseline: 1.4977x; 1.4977x over previous
//
#include <hip/hip_runtime.h>
#include <stdint.h>

// Koopman autoencoder — round 12 (MI355X / gfx950).
// R9 structure (pinned weights, 2 kernels) with 16-col waves: 8-wave blocks,
// weight slice = 16 VGPR/mat -> 5 mats = 80 VGPR -> <=128 total -> 16 waves/CU
// (2x R9's latency hiding). All skips via LDS; comb/Mfull transient regs.

typedef _Float16 h8 __attribute__((ext_vector_type(8)));
typedef _Float16 h4 __attribute__((ext_vector_type(4)));
typedef float    f4 __attribute__((ext_vector_type(4)));

#define ROWS_AUTO 104448
#define NT64      1632           // 64-row tiles
#define NUNITS    2432           // 1632 dec + 800 pred (32 rtiles x 25 chunks)

// half-element offsets inside wt (all mats stored as W^T [n][k])
#define WT_ENCW      0
#define WT_ENCWOUT   (4*16384)
#define WT_DECW      (5*16384)
#define WT_DECWOUT   (9*16384)
#define WT_COMB      (10*16384)  // (WencI@WdecI)^T [128][128]

// ws byte offsets
#define MFULL_OFF_B 0x60000      // f16 [50][128][128] (WencI@L^{s+1}@WdecI)^T
#define ACH_OFF_B   0x200000     // f32 [50][441]
#define PE_OFF_B    0x220000     // f16 LDS-image tiles [1632][16384B]
#define PET0_OFF_B  0x1C00000    // f16 [2048][128] compact pe at t=0 (chunk-linear)

// LDS buffers
#define H0 0
#define H1 16384
#define H2 32768
#define H3 49152
#define LDSE (49152 + 1280)      // k_enc: H0..H2 + 640 f16 biases
#define LDSD (65536 + 1280)      // k_decpred: H0..H3 + 640 f16 biases

#define hsw(rl, c) ((rl)*256 + ((((c)) ^ ((rl) & 7)) << 4))

// opaque pin: forbids rematerialization/sinking of weight loads
#define PIN4(B) asm volatile("" : "+v"(B[0]), "+v"(B[1]), "+v"(B[2]), "+v"(B[3]))

__device__ __forceinline__ f4 mfma16(h8 a, h8 b, f4 c) {
  return __builtin_amdgcn_mfma_f32_16x16x32_f16(a, b, c, 0, 0, 0);
}
__device__ __forceinline__ h8 cvt8(f4 a, f4 b) {
  h8 r;
  r[0]=(_Float16)a[0]; r[1]=(_Float16)a[1]; r[2]=(_Float16)a[2]; r[3]=(_Float16)a[3];
  r[4]=(_Float16)b[0]; r[5]=(_Float16)b[1]; r[6]=(_Float16)b[2]; r[7]=(_Float16)b[3];
  return r;
}
// wave's 16-col slice of a 128x128 W^T: B[ks] covers n=wbase+r15, k=ks*32+hi*8
__device__ __forceinline__ void loadW16(h8 B[4], const _Float16* gW, int wbase, int r15, int hi) {
#pragma unroll
  for (int ks = 0; ks < 4; ++ks)
    B[ks] = *(const h8*)(gW + (size_t)(wbase + r15)*128 + ks*32 + hi*8);
}

// SWAPPED operands: lane holds out[row=rt*16+r15][n=wbase+hi*4+d]
__device__ __forceinline__ void mm16(const char* sm, int hb, const h8 B[4],
                                     f4 acc[4], int r15, int hi) {
#pragma unroll
  for (int rt = 0; rt < 4; ++rt) acc[rt] = (f4){0,0,0,0};
#pragma unroll
  for (int ks = 0; ks < 4; ++ks) {
    int c = ks*4 + hi;
#pragma unroll
    for (int rt = 0; rt < 4; ++rt) {
      h8 a = *(const h8*)(sm + hb + hsw(rt*16 + r15, c));
      acc[rt] = mfma16(B[ks], a, acc[rt]);
    }
  }
}

// ReLU(acc + f16 bias) -> h[hb] (one h4 per rt per lane)
__device__ __forceinline__ void hw16s(char* sm, int hb, int wbase, const f4 acc[4],
                                      const _Float16* blh, int bo, int r15, int hi) {
  h4 bb = *(const h4*)(blh + bo + wbase + hi*4);
  int c = (wbase >> 3) + (hi >> 1), bo2 = (hi & 1) * 8;
#pragma unroll
  for (int rt = 0; rt < 4; ++rt) {
    int row = rt*16 + r15;
    h4 p;
#pragma unroll
    for (int d = 0; d < 4; ++d) p[d] = (_Float16)fmaxf(acc[rt][d] + (float)bb[d], 0.f);
    *(h4*)(sm + hb + row*256 + ((c ^ (row & 7)) << 4) + bo2) = p;
  }
}
// raw acc -> h[hb] (no bias/relu)
__device__ __forceinline__ void hw16a(char* sm, int hb, int wbase, const f4 acc[4],
                                      int r15, int hi) {
  int c = (wbase >> 3) + (hi >> 1), bo2 = (hi & 1) * 8;
#pragma unroll
  for (int rt = 0; rt < 4; ++rt) {
    int row = rt*16 + r15;
    h4 p;
#pragma unroll
    for (int d = 0; d < 4; ++d) p[d] = (_Float16)acc[rt][d];
    *(h4*)(sm + hb + row*256 + ((c ^ (row & 7)) << 4) + bo2) = p;
  }
}

// out = acc + bout + skip(LDS hskip) -> f32 trbuf (32KB at trb) -> global full lines
__device__ __forceinline__ void epi16(char* sm, int hskip, int trb, int wbase,
                                      const f4 acc[4], const _Float16* blh, int bout,
                                      float* dst, int rstride, int tid, int r15, int hi) {
  h4 bb = *(const h4*)(blh + bout + wbase + hi*4);
  int c = (wbase >> 3) + (hi >> 1), bo2 = (hi & 1) * 8;
  int q = (wbase >> 2) + hi;
#pragma unroll
  for (int rt = 0; rt < 4; ++rt) {
    int row = rt*16 + r15;
    h4 sk = *(const h4*)(sm + hskip + row*256 + ((c ^ (row & 7)) << 4) + bo2);
    f4 v;
#pragma unroll
    for (int d = 0; d < 4; ++d) v[d] = acc[rt][d] + (float)bb[d] + (float)sk[d];
    *(f4*)(sm + trb + row*512 + ((q ^ ((row & 7) << 2)) << 4)) = v;
  }
  __syncthreads();
#pragma unroll
  for (int i = 0; i < 4; ++i) {
    int idx = i*512 + tid, row = idx >> 5, qq = idx & 31;
    f4 v = *(const f4*)(sm + trb + row*512 + ((qq ^ ((row & 7) << 2)) << 4));
    *(f4*)(dst + (size_t)row*rstride + qq*4) = v;
  }
}

#define LAY(LIN, LOUT, BW, BO) do {                        \
    mm16(sm, LIN, BW, acc, r15, hi);                       \
    hw16s(sm, LOUT, wbase, acc, blh, BO, r15, hi);         \
    __syncthreads();                                       \
  } while (0)

// ---------------- prep kernels ----------------

__global__ __launch_bounds__(512) void k_prep(
    const float* __restrict__ encW, const float* __restrict__ encWout,
    const float* __restrict__ decW, const float* __restrict__ decWout,
    const float* __restrict__ L,
    _Float16* __restrict__ wt, float* __restrict__ ach) {
  __shared__ float chA[441], chB[441];
  int m = blockIdx.y, tid = threadIdx.x;
  if (m == 10) {
    if (blockIdx.x != 0) return;
    if (tid < 441) chA[tid] = L[tid];
    __syncthreads();
    for (int s = 0; s < 50; ++s) {
      if (tid < 441) ach[s*441 + tid] = chA[tid];
      if (s == 49) break;
      if (tid < 441) {
        int i = tid / 21, j = tid % 21; float a = 0.f;
        for (int k = 0; k < 21; ++k) a += chA[i*21 + k] * L[k*21 + j];
        chB[tid] = a;
      }
      __syncthreads();
      if (tid < 441) chA[tid] = chB[tid];
      __syncthreads();
    }
    return;
  }
  int idx = blockIdx.x*512 + tid;
  if (idx >= 16384) return;
  const float* src; _Float16* dst;
  if (m < 4)       { src = encW + m*16384;     dst = wt + WT_ENCW + m*16384; }
  else if (m == 4) { src = encWout;            dst = wt + WT_ENCWOUT; }
  else if (m < 9)  { src = decW + (m-5)*16384; dst = wt + WT_DECW + (m-5)*16384; }
  else             { src = decWout;            dst = wt + WT_DECWOUT; }
  int n = idx >> 7, k = idx & 127;
  dst[idx] = (_Float16)src[k*128 + n];            // W^T[n][k]
}

__global__ __launch_bounds__(512) void k_aux(
    const float* __restrict__ ach, const float* __restrict__ wencI,
    const float* __restrict__ wdecI,
    _Float16* __restrict__ mfull, _Float16* __restrict__ wt) {
  __shared__ float T1[2688];
  __shared__ float sa[441];
  int s = blockIdx.x, t = threadIdx.x;
  if (s < 50) {
    if (t < 441) sa[t] = ach[s*441 + t];
    __syncthreads();
    for (int idx = t; idx < 2688; idx += 512) {
      int k = idx / 21, j = idx % 21;
      float a = 0.f;
      for (int u = 0; u < 21; ++u) a += wencI[k*21 + u] * sa[u*21 + j];
      T1[idx] = a;
    }
  } else {
    for (int idx = t; idx < 2688; idx += 512) T1[idx] = wencI[idx];
  }
  __syncthreads();
  _Float16* dst = (s < 50) ? (mfull + (size_t)s*16384) : (wt + WT_COMB);
  for (int idx = t; idx < 16384; idx += 512) {    // M^T[n][k]
    int n = idx >> 7, k = idx & 127;
    float a = 0.f;
    for (int j = 0; j < 21; ++j) a += T1[k*21 + j] * wdecI[j*128 + n];
    dst[idx] = (_Float16)a;
  }
}

// ---------------- encoder: x -> pe image + compact pet0 ----------------

__global__ __launch_bounds__(512, 4) void k_enc(
    const float* __restrict__ x, const _Float16* __restrict__ wt,
    const float* __restrict__ enc_b, const float* __restrict__ enc_bout,
    _Float16* __restrict__ pe_ws, _Float16* __restrict__ pet0) {
  __shared__ char sm[LDSE];
  _Float16* blh = (_Float16*)(sm + 49152);
  int tid = threadIdx.x, lane = tid & 63;
  int r15 = lane & 15, hi = lane >> 4;
  int wbase = (tid >> 6) * 16;
  h8 B0[4], B1[4], B2[4], B3[4], B4[4];
  loadW16(B0, wt + WT_ENCW,           wbase, r15, hi);
  loadW16(B1, wt + WT_ENCW + 16384,   wbase, r15, hi);
  loadW16(B2, wt + WT_ENCW + 2*16384, wbase, r15, hi);
  loadW16(B3, wt + WT_ENCW + 3*16384, wbase, r15, hi);
  loadW16(B4, wt + WT_ENCWOUT,        wbase, r15, hi);
  PIN4(B0); PIN4(B1); PIN4(B2); PIN4(B3); PIN4(B4);
  for (int i = tid; i < 640; i += 512)
    blh[i] = (_Float16)(i < 512 ? enc_b[i] : enc_bout[i - 512]);
  f4 acc[4];

  for (int t = blockIdx.x; t < NT64; t += gridDim.x) {
    size_t rb = (size_t)t * 64;
#pragma unroll
    for (int i = 0; i < 2; ++i) {                 // stage x -> H0 (enc skip)
      int idx = i*512 + tid, rl = idx >> 4, c = idx & 15;
      const float* s = x + (rb + rl)*128 + c*8;
      f4 v0 = *(const f4*)s, v1 = *(const f4*)(s + 4);
      *(h8*)(sm + H0 + hsw(rl, c)) = cvt8(v0, v1);
    }
    __syncthreads();
    LAY(H0, H1, B0, 0); LAY(H1, H2, B1, 128);
    LAY(H2, H1, B2, 256); LAY(H1, H2, B3, 384);
    mm16(sm, H2, B4, acc, r15, hi);               // encWout
    {                                             // pe = acc + bout + x, in-place H0
      h4 bb = *(const h4*)(blh + 512 + wbase + hi*4);
      int c = (wbase >> 3) + (hi >> 1), bo2 = (hi & 1) * 8;
#pragma unroll
      for (int rt = 0; rt < 4; ++rt) {
        int row = rt*16 + r15;
        int soff = H0 + row*256 + ((c ^ (row & 7)) << 4) + bo2;
        h4 sk = *(const h4*)(sm + soff);
        h4 p;
#pragma unroll
        for (int d = 0; d < 4; ++d) p[d] = (_Float16)(acc[rt][d] + (float)bb[d] + (float)sk[d]);
        *(h4*)(sm + soff) = p;                    // lane-private slot: no race
      }
    }
    __syncthreads();
    {                                             // dump pe image + compact pet0
      char* g = (char*)(pe_ws) + (size_t)t*16384;
#pragma unroll
      for (int i = 0; i < 2; ++i) {
        int idx = i*512 + tid, off = idx*16;
        f4 v = *(const f4*)(sm + H0 + off);
        *(f4*)(g + off) = v;
        int rl = idx >> 4, slot = idx & 15;
        size_t rg = rb + (size_t)rl;
        if (rg % 51u == 0u) {
          int c = slot ^ (rl & 7);                // unswizzle -> chunk-linear
          *(f4*)((char*)pet0 + (rg/51u)*256 + c*16) = v;
        }
      }
    }
    __syncthreads();                              // dump reads done before next stage
  }
}

// ---------------- dec tiles + pred units ----------------

__global__ __launch_bounds__(512, 4) void k_decpred(
    const _Float16* __restrict__ wt, const _Float16* __restrict__ pe_ws,
    const _Float16* __restrict__ pet0, const _Float16* __restrict__ mfull,
    const float* __restrict__ dec_b, const float* __restrict__ dec_bout,
    float* __restrict__ out1, float* __restrict__ out2, float* __restrict__ out3) {
  __shared__ char sm[LDSD];
  _Float16* blh = (_Float16*)(sm + 65536);
  int tid = threadIdx.x, lane = tid & 63;
  int r15 = lane & 15, hi = lane >> 4;
  int wbase = (tid >> 6) * 16;
  h8 B0[4], B1[4], B2[4], B3[4], B4[4];
  loadW16(B0, wt + WT_DECW,           wbase, r15, hi);
  loadW16(B1, wt + WT_DECW + 16384,   wbase, r15, hi);
  loadW16(B2, wt + WT_DECW + 2*16384, wbase, r15, hi);
  loadW16(B3, wt + WT_DECW + 3*16384, wbase, r15, hi);
  loadW16(B4, wt + WT_DECWOUT,        wbase, r15, hi);
  PIN4(B0); PIN4(B1); PIN4(B2); PIN4(B3); PIN4(B4);
  for (int i = tid; i < 640; i += 512)
    blh[i] = (_Float16)(i < 512 ? dec_b[i] : dec_bout[i - 512]);
  f4 acc[4];

  for (int u = blockIdx.x; u < NUNITS; u += gridDim.x) {
    __syncthreads();                              // protect h bufs from prev-unit reads
    if (u < NT64) {
      // ---------- dec tile: pe -> out2 ; pd = pe@comb -> dec -> out1 ----------
      const char* src = (const char*)pe_ws + (size_t)u*16384;
#pragma unroll
      for (int i = 0; i < 2; ++i) {               // stage pe -> H0 (input+skip)
        int off = (i*512 + tid)*16;
        *(f4*)(sm + H0 + off) = *(const f4*)(src + off);
      }
      __syncthreads();
      // stream B: dec(pe)
      LAY(H0, H1, B0, 0); LAY(H1, H2, B1, 128);
      LAY(H2, H1, B2, 256); LAY(H1, H2, B3, 384);
      mm16(sm, H2, B4, acc, r15, hi);             // decWout
      __syncthreads();                            // H1/H2 reads done -> trbuf safe
      epi16(sm, H0, H1, wbase, acc, blh, 512,
            out2 + (size_t)u*64*128, 128, tid, r15, hi);
      {                                           // pd = pe @ comb (transient regs)
        h8 Bc[4];
        loadW16(Bc, wt + WT_COMB, wbase, r15, hi);
        mm16(sm, H0, Bc, acc, r15, hi);
      }
      hw16a(sm, H3, wbase, acc, r15, hi);         // pd -> H3 (input+skip)
      __syncthreads();
      // stream A: dec(pd)
      LAY(H3, H0, B0, 0); LAY(H0, H2, B1, 128);
      LAY(H2, H0, B2, 256); LAY(H0, H2, B3, 384);
      mm16(sm, H2, B4, acc, r15, hi);             // decWout
      __syncthreads();                            // H0/H2 reads done -> trbuf safe
      epi16(sm, H3, H1, wbase, acc, blh, 512,
            out1 + (size_t)u*64*128, 128, tid, r15, hi);
    } else {
      // ---------- pred unit: pet0 rtile x 2 Koopman steps ----------
      int p = u - NT64, rtile = p / 25, chunk = p % 25;
#pragma unroll
      for (int i = 0; i < 2; ++i) {               // stage pet0 -> H0
        int idx = i*512 + tid, rl = idx >> 4, c = idx & 15;
        f4 v = *(const f4*)((const char*)pet0 + (size_t)(rtile*64 + rl)*256 + c*16);
        *(f4*)(sm + H0 + hsw(rl, c)) = v;
      }
      __syncthreads();
      for (int s = chunk*2; s < chunk*2 + 2; ++s) {
        {
          h8 Bm[4];
          loadW16(Bm, mfull + (size_t)s*16384, wbase, r15, hi);
          mm16(sm, H0, Bm, acc, r15, hi);         // di = pet0 @ Mfull_s
        }
        hw16a(sm, H1, wbase, acc, r15, hi);       // di -> H1 (input+skip)
        __syncthreads();
        LAY(H1, H2, B0, 0); LAY(H2, H3, B1, 128);
        LAY(H3, H2, B2, 256); LAY(H2, H3, B3, 384);
        mm16(sm, H3, B4, acc, r15, hi);           // decWout
        __syncthreads();                          // H2/H3 reads done -> trbuf safe
        epi16(sm, H1, H2, wbase, acc, blh, 512,
              out3 + ((size_t)rtile*64*50 + s)*128, 50*128, tid, r15, hi);
        __syncthreads();                          // trbuf reads done before next s
      }
    }
  }
}

// ---------------- launch ----------------

extern "C" void kernel_launch(void* const* d_in, const int* in_sizes, int n_in,
                              void* d_out, int out_size, void* d_ws, size_t ws_size,
                              hipStream_t stream) {
  const float* x        = (const float*)d_in[0];
  const float* encW     = (const float*)d_in[1];
  const float* enc_b    = (const float*)d_in[2];
  const float* encWout  = (const float*)d_in[3];
  const float* enc_bout = (const float*)d_in[4];
  const float* decW     = (const float*)d_in[5];
  const float* dec_b    = (const float*)d_in[6];
  const float* decWout  = (const float*)d_in[7];
  const float* dec_bout = (const float*)d_in[8];
  const float* wencI    = (const float*)d_in[9];
  const float* L        = (const float*)d_in[10];
  const float* wdecI    = (const float*)d_in[11];

  char* ws = (char*)d_ws;
  _Float16* wt    = (_Float16*)ws;
  _Float16* mfull = (_Float16*)(ws + MFULL_OFF_B);
  float*    ach   = (float*)(ws + ACH_OFF_B);
  _Float16* pe_ws = (_Float16*)(ws + PE_OFF_B);
  _Float16* pet0  = (_Float16*)(ws + PET0_OFF_B);

  float* out1 = (float*)d_out;                       // autoencoder_output
  float* out2 = out1 + (size_t)ROWS_AUTO*128;        // outer_auto_output
  float* out3 = out2 + (size_t)ROWS_AUTO*128;        // predictions [2048][50][128]

  hipLaunchKernelGGL(k_prep, dim3(32, 11), dim3(512), 0, stream,
                     encW, encWout, decW, decWout, L, wt, ach);
  hipLaunchKernelGGL(k_aux, dim3(51), dim3(512), 0, stream,
                     ach, wencI, wdecI, mfull, wt);
  hipLaunchKernelGGL(k_enc, dim3(512), dim3(512), 0, stream,
                     x, wt, enc_b, enc_bout, pe_ws, pet0);
  hipLaunchKernelGGL(k_decpred, dim3(512), dim3(512), 0, stream,
                     wt, pe_ws, pet0, mfull, dec_b, dec_bout, out1, out2, out3);
}